// Round 1
// baseline (1484.961 us; speedup 1.0000x reference)
//
#include <hip/hip_runtime.h>
#include <math.h>

#define CCH 256
#define NBATCH 64
#define LLEN 4096
#define MTOT (NBATCH * LLEN)      // 262144
#define EPSV 1e-3f
#define NS_ITERS 5                // spectrum in [0.94,1.07] -> r4 ~ 1e-21, converged
#define GSPLIT 256
#define KSLICE (MTOT / GSPLIT)    // 1024 (stays within one n's row)

#define FMA16(ACC, av, bv)                                                   \
  ACC[0][0] += av.x * bv.x; ACC[0][1] += av.x * bv.y;                        \
  ACC[0][2] += av.x * bv.z; ACC[0][3] += av.x * bv.w;                        \
  ACC[1][0] += av.y * bv.x; ACC[1][1] += av.y * bv.y;                        \
  ACC[1][2] += av.y * bv.z; ACC[1][3] += av.y * bv.w;                        \
  ACC[2][0] += av.z * bv.x; ACC[2][1] += av.z * bv.y;                        \
  ACC[2][2] += av.z * bv.z; ACC[2][3] += av.z * bv.w;                        \
  ACC[3][0] += av.w * bv.x; ACC[3][1] += av.w * bv.y;                        \
  ACC[3][2] += av.w * bv.z; ACC[3][3] += av.w * bv.w;

#define ST8(SM, K0, C, v0, v1)                                               \
  SM[(K0) + 0][C] = v0.x; SM[(K0) + 1][C] = v0.y;                            \
  SM[(K0) + 2][C] = v0.z; SM[(K0) + 3][C] = v0.w;                            \
  SM[(K0) + 4][C] = v1.x; SM[(K0) + 5][C] = v1.y;                            \
  SM[(K0) + 6][C] = v1.z; SM[(K0) + 7][C] = v1.w;

// ---------------- mean over [N, L] per channel ----------------
__global__ void mean_kernel(const float* __restrict__ X, float* __restrict__ mean) {
  const int c = blockIdx.x, t = threadIdx.x;
  float s = 0.f;
  for (int n = 0; n < NBATCH; ++n) {
    const float4* p = (const float4*)(X + (size_t)(n * CCH + c) * LLEN);
    for (int j = t; j < LLEN / 4; j += 256) {
      float4 v = p[j];
      s += (v.x + v.y) + (v.z + v.w);
    }
  }
  for (int off = 32; off > 0; off >>= 1) s += __shfl_down(s, off, 64);
  __shared__ float red[4];
  const int wave = t >> 6, lane = t & 63;
  if (lane == 0) red[wave] = s;
  __syncthreads();
  if (t == 0) mean[c] = (red[0] + red[1] + red[2] + red[3]) * (1.0f / MTOT);
}

// ---------------- Gram: G = x @ x^T, symmetric 3-tile (128x128), split-K ----------------
// tiles: 0:(0,0) 1:(0,128) 2:(128,128); diagonal tiles load A once (B==A).
__global__ __launch_bounds__(256) void gram_kernel(const float* __restrict__ X,
                                                   float* __restrict__ G) {
  __shared__ float As[32][132];
  __shared__ float Bs[32][132];
  const int tid = threadIdx.x;
  const int tile = blockIdx.y;
  const int ca = (tile == 2) ? 128 : 0;
  const int cb = (tile == 0) ? 0 : 128;
  const bool diag = (ca == cb);
  const int k0 = blockIdx.x * KSLICE;
  const int n = k0 >> 12;
  const int l0 = k0 & 4095;
  const int lc = tid >> 1;               // 0..127 channel within tile
  const int lk = (tid & 1) * 16;         // 0 or 16
  const int ty = tid >> 4, tx = tid & 15;
  const int ci = ty * 4, cj = tx * 4;
  const float* Xn = X + (size_t)n * CCH * LLEN;
  float acc00[4][4] = {{0.f}}, acc01[4][4] = {{0.f}};
  float acc10[4][4] = {{0.f}}, acc11[4][4] = {{0.f}};
  for (int kc = 0; kc < KSLICE; kc += 32) {
    __syncthreads();
    {
      const float* pa = Xn + (size_t)(ca + lc) * LLEN + l0 + kc + lk;
      float4 a0 = *(const float4*)(pa + 0);
      float4 a1 = *(const float4*)(pa + 4);
      float4 a2 = *(const float4*)(pa + 8);
      float4 a3 = *(const float4*)(pa + 12);
      ST8(As, lk + 0, lc, a0, a1);
      ST8(As, lk + 8, lc, a2, a3);
      if (!diag) {
        const float* pb = Xn + (size_t)(cb + lc) * LLEN + l0 + kc + lk;
        float4 b0 = *(const float4*)(pb + 0);
        float4 b1 = *(const float4*)(pb + 4);
        float4 b2 = *(const float4*)(pb + 8);
        float4 b3 = *(const float4*)(pb + 12);
        ST8(Bs, lk + 0, lc, b0, b1);
        ST8(Bs, lk + 8, lc, b2, b3);
      }
    }
    __syncthreads();
    const float (*Bp)[132] = diag ? As : Bs;
#pragma unroll
    for (int k = 0; k < 32; ++k) {
      float4 a0 = *(const float4*)&As[k][ci];
      float4 a1 = *(const float4*)&As[k][ci + 64];
      float4 b0 = *(const float4*)&Bp[k][cj];
      float4 b1 = *(const float4*)&Bp[k][cj + 64];
      FMA16(acc00, a0, b0);
      FMA16(acc01, a0, b1);
      FMA16(acc10, a1, b0);
      FMA16(acc11, a1, b1);
    }
  }
#pragma unroll
  for (int r = 0; r < 4; ++r) {
#pragma unroll
    for (int s = 0; s < 4; ++s) {
      atomicAdd(&G[(size_t)(ca + ci + r) * CCH + (cb + cj + s)], acc00[r][s]);
      atomicAdd(&G[(size_t)(ca + ci + r) * CCH + (cb + cj + s + 64)], acc01[r][s]);
      atomicAdd(&G[(size_t)(ca + ci + r + 64) * CCH + (cb + cj + s)], acc10[r][s]);
      atomicAdd(&G[(size_t)(ca + ci + r + 64) * CCH + (cb + cj + s + 64)], acc11[r][s]);
    }
  }
}

// ---------------- fused sigma + trace + normalize: Y0 = sigma / (trace/C) ----------------
// G holds raw x x^T only in regions (r<128||c>=128); mirror for the rest.
__global__ void norm_kernel(const float* __restrict__ G, const float* __restrict__ mean,
                            float* __restrict__ Y, float* __restrict__ rs) {
  const int r = blockIdx.x, t = threadIdx.x;
  float d = G[(size_t)t * 257] * (1.0f / MTOT) - mean[t] * mean[t] + EPSV;
  for (int off = 32; off > 0; off >>= 1) d += __shfl_down(d, off, 64);
  __shared__ float red[4];
  const int wave = t >> 6, lane = t & 63;
  if (lane == 0) red[wave] = d;
  __syncthreads();
  const float s = (red[0] + red[1] + red[2] + red[3]) * (1.0f / CCH);
  const int cc = t;
  const float graw = (r >= 128 && cc < 128) ? G[(size_t)cc * CCH + r]
                                            : G[(size_t)r * CCH + cc];
  const float v = graw * (1.0f / MTOT) - mean[r] * mean[cc] + (r == cc ? EPSV : 0.f);
  Y[(size_t)r * CCH + cc] = v / s;
  if (r == 0 && cc == 0) rs[0] = 1.0f / sqrtf(s);
}

// ---------------- NS iter 0 specialization (Z=I): T = 3I - Y, Z1 = 0.5*T ----------------
__global__ void ns0_kernel(const float* __restrict__ Y, float* __restrict__ T,
                           float* __restrict__ Z) {
  const int idx = blockIdx.x * 256 + threadIdx.x;
  const int r = idx >> 8, c = idx & 255;
  const float t = (r == c ? 3.0f : 0.0f) - Y[idx];
  T[idx] = t;
  Z[idx] = 0.5f * t;
}

// upper-triangle tile index -> (bi,bj) for 4x4 tile grid (10 tiles)
__device__ __forceinline__ void tile_ij(int t, int& bi, int& bj) {
  if (t < 4)      { bi = 0; bj = t; }
  else if (t < 7) { bi = 1; bj = t - 3; }
  else if (t < 9) { bi = 2; bj = t - 5; }
  else            { bi = 3; bj = 3; }
}

// 64x64-tile 256^3 matmul, C = alpha*A*B + beta*I, result symmetric -> mirror write
__device__ __forceinline__ void tile_mm64_sym(const float* __restrict__ A,
                                              const float* __restrict__ B,
                                              float* __restrict__ Cm,
                                              int bi, int bj, float alpha, float beta) {
  __shared__ float As[32][68];
  __shared__ float Bs[32][68];
  const int tid = threadIdx.x;
  const int r0 = bi * 64, c0 = bj * 64;
  const int lc = tid >> 2;
  const int lk = (tid & 3) * 8;
  const int kx = tid >> 3;
  const int lx = (tid & 7) * 8;
  const int ty = tid >> 4, tx = tid & 15;
  const int ci = ty * 4, cj = tx * 4;
  float acc[4][4] = {{0.f}};
  for (int kc = 0; kc < CCH; kc += 32) {
    __syncthreads();
    const float* pa = A + (size_t)(r0 + lc) * CCH + kc + lk;
    float4 v0 = *(const float4*)pa;
    float4 v1 = *(const float4*)(pa + 4);
    ST8(As, lk, lc, v0, v1);
    const float* pb = B + (size_t)(kc + kx) * CCH + c0 + lx;
    *(float4*)&Bs[kx][lx]     = *(const float4*)pb;
    *(float4*)&Bs[kx][lx + 4] = *(const float4*)(pb + 4);
    __syncthreads();
#pragma unroll
    for (int k = 0; k < 32; ++k) {
      float4 a = *(const float4*)&As[k][ci];
      float4 b = *(const float4*)&Bs[k][cj];
      FMA16(acc, a, b);
    }
  }
#pragma unroll
  for (int r = 0; r < 4; ++r) {
    const int gr = r0 + ci + r;
#pragma unroll
    for (int s = 0; s < 4; ++s) {
      const int gc = c0 + cj + s;
      float v = alpha * acc[r][s];
      if (gr == gc) v += beta;
      Cm[(size_t)gr * CCH + gc] = v;
      if (bi != bj) Cm[(size_t)gc * CCH + gr] = v;
    }
  }
}

// Yn = 0.5 * Y * T  (iter-0 tail)
__global__ __launch_bounds__(256) void nsY_kernel(const float* __restrict__ Y,
                                                  const float* __restrict__ T,
                                                  float* __restrict__ Yn) {
  int bi, bj; tile_ij(blockIdx.x, bi, bj);
  tile_mm64_sym(Y, T, Yn, bi, bj, 0.5f, 0.0f);
}

// T = 3I - Z*Y  (upper tiles only, mirrored)
__global__ __launch_bounds__(256) void nsT_kernel(const float* __restrict__ Z,
                                                  const float* __restrict__ Y,
                                                  float* __restrict__ T) {
  int bi, bj; tile_ij(blockIdx.x, bi, bj);
  tile_mm64_sym(Z, Y, T, bi, bj, -1.0f, 3.0f);
}

// Yn = 0.5*Y*T (blocks 0..9), Zn = 0.5*T*Z (blocks 10..19)
__global__ __launch_bounds__(256) void nsYZ_kernel(const float* __restrict__ Y,
                                                   const float* __restrict__ Z,
                                                   const float* __restrict__ T,
                                                   float* __restrict__ Yn,
                                                   float* __restrict__ Zn) {
  const int bid = blockIdx.x;
  int bi, bj; tile_ij(bid < 10 ? bid : bid - 10, bi, bj);
  if (bid < 10) tile_mm64_sym(Y, T, Yn, bi, bj, 0.5f, 0.0f);
  else          tile_mm64_sym(T, Z, Zn, bi, bj, 0.5f, 0.0f);
}

// bias[c] = rs * sum_k Z[c,k] * mean[k]
__global__ void bias_kernel(const float* __restrict__ Z, const float* __restrict__ mean,
                            const float* __restrict__ rs, float* __restrict__ bias) {
  const int c = threadIdx.x;
  float s = 0.f;
  const float4* zp = (const float4*)(Z + (size_t)c * CCH);
  const float4* mp = (const float4*)mean;
  for (int k = 0; k < CCH / 4; ++k) {
    float4 z = zp[k], m = mp[k];
    s += z.x * m.x + z.y * m.y + z.z * m.z + z.w * m.w;
  }
  bias[c] = s * rs[0];
}

// out[n,c,l] = rs * sum_k Z[c,k] * X[n,k,l] - bias[c]
// 256(c) x 64(l) tile per block, 8x8 per thread -> FMA:ds_read = 128:48 cyc per k
__global__ __launch_bounds__(256) void whiten_kernel(const float* __restrict__ X,
                                                     const float* __restrict__ Z,
                                                     const float* __restrict__ rs,
                                                     const float* __restrict__ bias,
                                                     float* __restrict__ out) {
  __shared__ float Ws[32][260];
  __shared__ float Xs[32][68];
  const int tid = threadIdx.x;
  const int l0 = blockIdx.x * 64;
  const int n  = blockIdx.y;
  const int cg = tid >> 3;          // 0..31
  const int lg = tid & 7;           // 0..7
  const int ci = cg * 4;            // rows ci..ci+3 and ci+128..ci+131
  const int lj = lg * 4;            // cols lj..lj+3 and lj+32..lj+35
  const int kx = tid >> 3;          // 0..31  (X staging row)
  const int lx = (tid & 7) * 8;     // 0..56  (X staging col)
  const float* Xn = X + (size_t)n * CCH * LLEN;
  float acc00[4][4] = {{0.f}}, acc01[4][4] = {{0.f}};
  float acc10[4][4] = {{0.f}}, acc11[4][4] = {{0.f}};
  for (int kc = 0; kc < CCH; kc += 32) {
    __syncthreads();
    {
      const float* pz = Z + (size_t)tid * CCH + kc;
#pragma unroll
      for (int i = 0; i < 8; ++i) {
        float4 z = *(const float4*)(pz + i * 4);
        Ws[i * 4 + 0][tid] = z.x;
        Ws[i * 4 + 1][tid] = z.y;
        Ws[i * 4 + 2][tid] = z.z;
        Ws[i * 4 + 3][tid] = z.w;
      }
      const float* px = Xn + (size_t)(kc + kx) * LLEN + l0 + lx;
      *(float4*)&Xs[kx][lx]     = *(const float4*)px;
      *(float4*)&Xs[kx][lx + 4] = *(const float4*)(px + 4);
    }
    __syncthreads();
#pragma unroll
    for (int k = 0; k < 32; ++k) {
      float4 a0 = *(const float4*)&Ws[k][ci];
      float4 a1 = *(const float4*)&Ws[k][ci + 128];
      float4 b0 = *(const float4*)&Xs[k][lj];
      float4 b1 = *(const float4*)&Xs[k][lj + 32];
      FMA16(acc00, a0, b0);
      FMA16(acc01, a0, b1);
      FMA16(acc10, a1, b0);
      FMA16(acc11, a1, b1);
    }
  }
  const float rsv = rs[0];
#pragma unroll
  for (int r = 0; r < 4; ++r) {
    const int clo = ci + r, chi = ci + 128 + r;
    const float blo = bias[clo], bhi = bias[chi];
    float* olo = out + (size_t)n * CCH * LLEN + (size_t)clo * LLEN + l0;
    float* ohi = out + (size_t)n * CCH * LLEN + (size_t)chi * LLEN + l0;
    float4 o;
    o.x = rsv * acc00[r][0] - blo; o.y = rsv * acc00[r][1] - blo;
    o.z = rsv * acc00[r][2] - blo; o.w = rsv * acc00[r][3] - blo;
    *(float4*)(olo + lj) = o;
    o.x = rsv * acc01[r][0] - blo; o.y = rsv * acc01[r][1] - blo;
    o.z = rsv * acc01[r][2] - blo; o.w = rsv * acc01[r][3] - blo;
    *(float4*)(olo + lj + 32) = o;
    o.x = rsv * acc10[r][0] - bhi; o.y = rsv * acc10[r][1] - bhi;
    o.z = rsv * acc10[r][2] - bhi; o.w = rsv * acc10[r][3] - bhi;
    *(float4*)(ohi + lj) = o;
    o.x = rsv * acc11[r][0] - bhi; o.y = rsv * acc11[r][1] - bhi;
    o.z = rsv * acc11[r][2] - bhi; o.w = rsv * acc11[r][3] - bhi;
    *(float4*)(ohi + lj + 32) = o;
  }
}

extern "C" void kernel_launch(void* const* d_in, const int* in_sizes, int n_in,
                              void* d_out, int out_size, void* d_ws, size_t ws_size,
                              hipStream_t stream) {
  const float* X = (const float*)d_in[0];
  float* out = (float*)d_out;
  float* ws = (float*)d_ws;
  const size_t MSZ = (size_t)CCH * CCH;   // 65536 floats

  float* G    = ws;
  float* Y0   = ws + 1 * MSZ;
  float* Y1   = ws + 2 * MSZ;
  float* Z0   = ws + 3 * MSZ;
  float* Z1   = ws + 4 * MSZ;
  float* T    = ws + 5 * MSZ;
  float* mean = ws + 6 * MSZ;
  float* bias = mean + CCH;
  float* scal = bias + CCH;               // [0] = 1/sqrt(s)

  hipMemsetAsync(G, 0, MSZ * sizeof(float), stream);

  mean_kernel<<<CCH, 256, 0, stream>>>(X, mean);
  gram_kernel<<<dim3(GSPLIT, 3), 256, 0, stream>>>(X, G);
  norm_kernel<<<256, 256, 0, stream>>>(G, mean, Y0, scal);

  // NS iter 0 (Z = I): T = 3I - Y0 (elementwise), Z0 = 0.5*T, Y1 = 0.5*Y0*T
  ns0_kernel<<<256, 256, 0, stream>>>(Y0, T, Z0);
  nsY_kernel<<<10, 256, 0, stream>>>(Y0, T, Y1);

  float* Yc = Y1; float* Zc = Z0; float* Yn = Y0; float* Zn = Z1;
  for (int it = 1; it < NS_ITERS; ++it) {
    nsT_kernel<<<10, 256, 0, stream>>>(Zc, Yc, T);
    nsYZ_kernel<<<20, 256, 0, stream>>>(Yc, Zc, T, Yn, Zn);
    float* tmp;
    tmp = Yc; Yc = Yn; Yn = tmp;
    tmp = Zc; Zc = Zn; Zn = tmp;
  }

  bias_kernel<<<1, CCH, 0, stream>>>(Zc, mean, scal, bias);
  whiten_kernel<<<dim3(LLEN / 64, NBATCH), 256, 0, stream>>>(X, Zc, scal, bias, out);
}

// Round 2
// 881.859 us; speedup vs baseline: 1.6839x; 1.6839x over previous
//
#include <hip/hip_runtime.h>
#include <math.h>

#define CCH 256
#define NBATCH 64
#define LLEN 4096
#define MTOT (NBATCH * LLEN)      // 262144
#define EPSV 1e-3f
#define NS_ITERS 5                // spectrum in [0.94,1.07] -> r4 ~ 1e-21, converged
#define GSPLIT 128
#define KSLICE (MTOT / GSPLIT)    // 2048 (stays within one n's row)

typedef float f32x4 __attribute__((ext_vector_type(4)));
typedef short short8 __attribute__((ext_vector_type(8)));

union U8 { ushort u[8]; short8 v; };

// ---- fp32 -> bf16 (RNE) split helpers (bit ops; no __bf16 dependency) ----
__device__ __forceinline__ ushort f2bf(float x) {
  union { float f; uint u; } c; c.f = x;
  uint u = c.u + 0x7FFFu + ((c.u >> 16) & 1u);
  return (ushort)(u >> 16);
}
__device__ __forceinline__ float bf2f(ushort h) {
  union { uint u; float f; } c; c.u = ((uint)h) << 16;
  return c.f;
}
__device__ __forceinline__ void split1(float x, ushort& h, ushort& l) {
  h = f2bf(x);
  l = f2bf(x - bf2f(h));
}
__device__ __forceinline__ void split4(const float4 v, ushort* h, ushort* l, float& s) {
  split1(v.x, h[0], l[0]); split1(v.y, h[1], l[1]);
  split1(v.z, h[2], l[2]); split1(v.w, h[3], l[3]);
  s += (v.x + v.y) + (v.z + v.w);
}

#define FMA16(ACC, av, bv)                                                   \
  ACC[0][0] += av.x * bv.x; ACC[0][1] += av.x * bv.y;                        \
  ACC[0][2] += av.x * bv.z; ACC[0][3] += av.x * bv.w;                        \
  ACC[1][0] += av.y * bv.x; ACC[1][1] += av.y * bv.y;                        \
  ACC[1][2] += av.y * bv.z; ACC[1][3] += av.y * bv.w;                        \
  ACC[2][0] += av.z * bv.x; ACC[2][1] += av.z * bv.y;                        \
  ACC[2][2] += av.z * bv.z; ACC[2][3] += av.z * bv.w;                        \
  ACC[3][0] += av.w * bv.x; ACC[3][1] += av.w * bv.y;                        \
  ACC[3][2] += av.w * bv.z; ACC[3][3] += av.w * bv.w;

#define ST8(SM, K0, C, v0, v1)                                               \
  SM[(K0) + 0][C] = v0.x; SM[(K0) + 1][C] = v0.y;                            \
  SM[(K0) + 2][C] = v0.z; SM[(K0) + 3][C] = v0.w;                            \
  SM[(K0) + 4][C] = v1.x; SM[(K0) + 5][C] = v1.y;                            \
  SM[(K0) + 6][C] = v1.z; SM[(K0) + 7][C] = v1.w;

// ================= Gram via MFMA bf16x2: G = x x^T (3 sym 128x128 tiles) =======
// Also accumulates per-channel raw sums (for mean) during A staging (tiles 0,2).
__global__ __launch_bounds__(256) void gram_kernel(const float* __restrict__ X,
                                                   float* __restrict__ G,
                                                   float* __restrict__ msum) {
  __shared__ __align__(16) ushort Ah[128 * 40];
  __shared__ __align__(16) ushort Al[128 * 40];
  __shared__ __align__(16) ushort Bh[128 * 40];
  __shared__ __align__(16) ushort Bl[128 * 40];
  const int tid = threadIdx.x;
  const int tile = blockIdx.y;
  const int ca = (tile == 2) ? 128 : 0;
  const int cb = (tile == 0) ? 0 : 128;
  const bool diag = (ca == cb);
  const int k0 = blockIdx.x * KSLICE;
  const int n = k0 >> 12;
  const int l0 = k0 & 4095;
  const int row = tid >> 1, half = tid & 1;       // staging: 128 rows x 2 halves of 16 k
  const int lane = tid & 63, wave = tid >> 6;
  const int wr = wave >> 1, wc = wave & 1;        // wave -> 64x64 sub-tile
  const int lrow = lane & 15, kblk = lane >> 4;
  const float* Xn = X + (size_t)n * CCH * LLEN;
  f32x4 acc[4][4] = {};
  float ms = 0.f, dummy = 0.f;
  for (int kc = 0; kc < KSLICE; kc += 32) {
    __syncthreads();
    {
      const float* pa = Xn + (size_t)(ca + row) * LLEN + l0 + kc + half * 16;
      float4 a0 = *(const float4*)(pa + 0);
      float4 a1 = *(const float4*)(pa + 4);
      float4 a2 = *(const float4*)(pa + 8);
      float4 a3 = *(const float4*)(pa + 12);
      U8 H0, H1, L0, L1;
      split4(a0, H0.u + 0, L0.u + 0, ms);
      split4(a1, H0.u + 4, L0.u + 4, ms);
      split4(a2, H1.u + 0, L1.u + 0, ms);
      split4(a3, H1.u + 4, L1.u + 4, ms);
      const int so = row * 40 + half * 16;
      *(short8*)&Ah[so] = H0.v;  *(short8*)&Ah[so + 8] = H1.v;
      *(short8*)&Al[so] = L0.v;  *(short8*)&Al[so + 8] = L1.v;
      if (!diag) {
        const float* pb = Xn + (size_t)(cb + row) * LLEN + l0 + kc + half * 16;
        float4 b0 = *(const float4*)(pb + 0);
        float4 b1 = *(const float4*)(pb + 4);
        float4 b2 = *(const float4*)(pb + 8);
        float4 b3 = *(const float4*)(pb + 12);
        U8 P0, P1, Q0, Q1;
        split4(b0, P0.u + 0, Q0.u + 0, dummy);
        split4(b1, P0.u + 4, Q0.u + 4, dummy);
        split4(b2, P1.u + 0, Q1.u + 0, dummy);
        split4(b3, P1.u + 4, Q1.u + 4, dummy);
        *(short8*)&Bh[so] = P0.v;  *(short8*)&Bh[so + 8] = P1.v;
        *(short8*)&Bl[so] = Q0.v;  *(short8*)&Bl[so + 8] = Q1.v;
      }
    }
    __syncthreads();
    short8 ah[4], al_[4], bh[4], bl_[4];
    const ushort* BhP = diag ? Ah : Bh;
    const ushort* BlP = diag ? Al : Bl;
#pragma unroll
    for (int i = 0; i < 4; ++i) {
      const int off = (wr * 64 + i * 16 + lrow) * 40 + kblk * 8;
      ah[i]  = *(const short8*)&Ah[off];
      al_[i] = *(const short8*)&Al[off];
    }
#pragma unroll
    for (int j = 0; j < 4; ++j) {
      const int off = (wc * 64 + j * 16 + lrow) * 40 + kblk * 8;
      bh[j]  = *(const short8*)&BhP[off];
      bl_[j] = *(const short8*)&BlP[off];
    }
#pragma unroll
    for (int i = 0; i < 4; ++i) {
#pragma unroll
      for (int j = 0; j < 4; ++j) {
        acc[i][j] = __builtin_amdgcn_mfma_f32_16x16x32_bf16(ah[i],  bh[j],  acc[i][j], 0, 0, 0);
        acc[i][j] = __builtin_amdgcn_mfma_f32_16x16x32_bf16(ah[i],  bl_[j], acc[i][j], 0, 0, 0);
        acc[i][j] = __builtin_amdgcn_mfma_f32_16x16x32_bf16(al_[i], bh[j],  acc[i][j], 0, 0, 0);
      }
    }
  }
  if (tile != 1) atomicAdd(&msum[ca + row], ms);
#pragma unroll
  for (int i = 0; i < 4; ++i) {
#pragma unroll
    for (int j = 0; j < 4; ++j) {
#pragma unroll
      for (int r = 0; r < 4; ++r) {
        const int grow = ca + wr * 64 + i * 16 + kblk * 4 + r;
        const int gcol = cb + wc * 64 + j * 16 + lrow;
        atomicAdd(&G[(size_t)grow * CCH + gcol], acc[i][j][r]);
      }
    }
  }
}

// ---- fused sigma + trace + normalize: Y0 = sigma / (trace/C), rs = 1/sqrt ----
__global__ void norm_kernel(const float* __restrict__ G, const float* __restrict__ msum,
                            float* __restrict__ Y, float* __restrict__ rs) {
  const int r = blockIdx.x, t = threadIdx.x;
  const float invM = 1.0f / MTOT;
  const float mt = msum[t] * invM;
  float d = G[(size_t)t * 257] * invM - mt * mt + EPSV;
  for (int off = 32; off > 0; off >>= 1) d += __shfl_down(d, off, 64);
  __shared__ float red[4];
  const int wave = t >> 6, lane = t & 63;
  if (lane == 0) red[wave] = d;
  __syncthreads();
  const float s = (red[0] + red[1] + red[2] + red[3]) * (1.0f / CCH);
  const int cc = t;
  const float graw = (r >= 128 && cc < 128) ? G[(size_t)cc * CCH + r]
                                            : G[(size_t)r * CCH + cc];
  const float mr = msum[r] * invM;
  const float v = graw * invM - mr * mt + (r == cc ? EPSV : 0.f);
  Y[(size_t)r * CCH + cc] = v / s;
  if (r == 0 && cc == 0) rs[0] = 1.0f / sqrtf(s);
}

// ---- NS iter 0 (Z=I): T = 3I - Y, Z = 0.5*T ----
__global__ void ns0_kernel(const float* __restrict__ Y, float* __restrict__ T,
                           float* __restrict__ Z) {
  const int idx = blockIdx.x * 256 + threadIdx.x;
  const int r = idx >> 8, c = idx & 255;
  const float t = (r == c ? 3.0f : 0.0f) - Y[idx];
  T[idx] = t;
  Z[idx] = 0.5f * t;
}

__device__ __forceinline__ void tile_ij(int t, int& bi, int& bj) {
  if (t < 4)      { bi = 0; bj = t; }
  else if (t < 7) { bi = 1; bj = t - 3; }
  else if (t < 9) { bi = 2; bj = t - 5; }
  else            { bi = 3; bj = 3; }
}

// 64x64-tile 256^3 fp32 matmul, C = alpha*A*B + beta*I, symmetric mirror write
__device__ __forceinline__ void tile_mm64_sym(const float* __restrict__ A,
                                              const float* __restrict__ B,
                                              float* __restrict__ Cm,
                                              int bi, int bj, float alpha, float beta) {
  __shared__ float As[32][68];
  __shared__ float Bs[32][68];
  const int tid = threadIdx.x;
  const int r0 = bi * 64, c0 = bj * 64;
  const int lc = tid >> 2;
  const int lk = (tid & 3) * 8;
  const int kx = tid >> 3;
  const int lx = (tid & 7) * 8;
  const int ty = tid >> 4, tx = tid & 15;
  const int ci = ty * 4, cj = tx * 4;
  float acc[4][4] = {{0.f}};
  for (int kc = 0; kc < CCH; kc += 32) {
    __syncthreads();
    const float* pa = A + (size_t)(r0 + lc) * CCH + kc + lk;
    float4 v0 = *(const float4*)pa;
    float4 v1 = *(const float4*)(pa + 4);
    ST8(As, lk, lc, v0, v1);
    const float* pb = B + (size_t)(kc + kx) * CCH + c0 + lx;
    *(float4*)&Bs[kx][lx]     = *(const float4*)pb;
    *(float4*)&Bs[kx][lx + 4] = *(const float4*)(pb + 4);
    __syncthreads();
#pragma unroll
    for (int k = 0; k < 32; ++k) {
      float4 a = *(const float4*)&As[k][ci];
      float4 b = *(const float4*)&Bs[k][cj];
      FMA16(acc, a, b);
    }
  }
#pragma unroll
  for (int r = 0; r < 4; ++r) {
    const int gr = r0 + ci + r;
#pragma unroll
    for (int s = 0; s < 4; ++s) {
      const int gc = c0 + cj + s;
      float v = alpha * acc[r][s];
      if (gr == gc) v += beta;
      Cm[(size_t)gr * CCH + gc] = v;
      if (bi != bj) Cm[(size_t)gc * CCH + gr] = v;
    }
  }
}

__global__ __launch_bounds__(256) void nsY_kernel(const float* __restrict__ Y,
                                                  const float* __restrict__ T,
                                                  float* __restrict__ Yn) {
  int bi, bj; tile_ij(blockIdx.x, bi, bj);
  tile_mm64_sym(Y, T, Yn, bi, bj, 0.5f, 0.0f);
}

__global__ __launch_bounds__(256) void nsT_kernel(const float* __restrict__ Z,
                                                  const float* __restrict__ Y,
                                                  float* __restrict__ T) {
  int bi, bj; tile_ij(blockIdx.x, bi, bj);
  tile_mm64_sym(Z, Y, T, bi, bj, -1.0f, 3.0f);
}

__global__ __launch_bounds__(256) void nsYZ_kernel(const float* __restrict__ Y,
                                                   const float* __restrict__ Z,
                                                   const float* __restrict__ T,
                                                   float* __restrict__ Yn,
                                                   float* __restrict__ Zn) {
  const int bid = blockIdx.x;
  int bi, bj; tile_ij(bid < 10 ? bid : bid - 10, bi, bj);
  if (bid < 10) tile_mm64_sym(Y, T, Yn, bi, bj, 0.5f, 0.0f);
  else          tile_mm64_sym(T, Z, Zn, bi, bj, 0.5f, 0.0f);
}

// ---- WM = rs * Z, split to bf16 hi/lo ----
__global__ void wmsplit_kernel(const float* __restrict__ Z, const float* __restrict__ rs,
                               ushort* __restrict__ WMh, ushort* __restrict__ WMl) {
  const int idx = blockIdx.x * 256 + threadIdx.x;
  const float w = Z[idx] * rs[0];
  ushort h, l; split1(w, h, l);
  WMh[idx] = h; WMl[idx] = l;
}

// ---- bias[c] = rs * sum_k Z[c,k] * mean[k] ----
__global__ void bias_kernel(const float* __restrict__ Z, const float* __restrict__ msum,
                            const float* __restrict__ rs, float* __restrict__ bias) {
  const int c = threadIdx.x;
  const float invM = 1.0f / MTOT;
  float s = 0.f;
  const float4* zp = (const float4*)(Z + (size_t)c * CCH);
  const float4* mp = (const float4*)msum;
  for (int k = 0; k < CCH / 4; ++k) {
    float4 z = zp[k], m = mp[k];
    s += z.x * m.x + z.y * m.y + z.z * m.z + z.w * m.w;
  }
  bias[c] = s * invM * rs[0];
}

// ================= whiten via MFMA: out[n,c,l] = sum_k WM[c,k] X[n,k,l] - bias[c]
// Block: 256 c x 64 l.  A-frags (WM hi/lo) direct from L2; X staged transposed in LDS.
__global__ __launch_bounds__(256) void whiten_kernel(const float* __restrict__ X,
                                                     const ushort* __restrict__ WMh,
                                                     const ushort* __restrict__ WMl,
                                                     const float* __restrict__ bias,
                                                     float* __restrict__ out) {
  __shared__ __align__(16) ushort XTh[64 * 40];
  __shared__ __align__(16) ushort XTl[64 * 40];
  __shared__ float biasS[256];
  const int tid = threadIdx.x;
  const int l0 = blockIdx.x * 64;
  const int n  = blockIdx.y;
  const int lane = tid & 63, w = tid >> 6;
  const int lrow = lane & 15, kblk = lane >> 4;
  const int sl = tid & 63, kq = tid >> 6;        // staging: 64 l-cols x 4 kp-quarters
  const float* Xn = X + (size_t)n * CCH * LLEN;
  biasS[tid] = bias[tid];
  f32x4 acc[4][4] = {};
  for (int kc = 0; kc < CCH; kc += 32) {
    __syncthreads();
#pragma unroll
    for (int i = 0; i < 4; ++i) {
      const int kp = kq * 4 + i;                 // k-pair index 0..15
      const float x0 = Xn[(size_t)(kc + 2 * kp) * LLEN + l0 + sl];
      const float x1 = Xn[(size_t)(kc + 2 * kp + 1) * LLEN + l0 + sl];
      ushort h0, q0, h1, q1;
      split1(x0, h0, q0); split1(x1, h1, q1);
      *(uint*)&XTh[sl * 40 + 2 * kp] = (uint)h0 | ((uint)h1 << 16);
      *(uint*)&XTl[sl * 40 + 2 * kp] = (uint)q0 | ((uint)q1 << 16);
    }
    __syncthreads();
    short8 ah[4], al_[4], bh[4], bl_[4];
#pragma unroll
    for (int i = 0; i < 4; ++i) {
      const size_t off = (size_t)(w * 64 + i * 16 + lrow) * CCH + kc + kblk * 8;
      ah[i]  = *(const short8*)(WMh + off);
      al_[i] = *(const short8*)(WMl + off);
    }
#pragma unroll
    for (int j = 0; j < 4; ++j) {
      const int off = (j * 16 + lrow) * 40 + kblk * 8;
      bh[j]  = *(const short8*)&XTh[off];
      bl_[j] = *(const short8*)&XTl[off];
    }
#pragma unroll
    for (int i = 0; i < 4; ++i) {
#pragma unroll
      for (int j = 0; j < 4; ++j) {
        acc[i][j] = __builtin_amdgcn_mfma_f32_16x16x32_bf16(ah[i],  bh[j],  acc[i][j], 0, 0, 0);
        acc[i][j] = __builtin_amdgcn_mfma_f32_16x16x32_bf16(ah[i],  bl_[j], acc[i][j], 0, 0, 0);
        acc[i][j] = __builtin_amdgcn_mfma_f32_16x16x32_bf16(al_[i], bh[j],  acc[i][j], 0, 0, 0);
      }
    }
  }
  float* outn = out + (size_t)n * CCH * LLEN;
#pragma unroll
  for (int i = 0; i < 4; ++i) {
#pragma unroll
    for (int r = 0; r < 4; ++r) {
      const int c = w * 64 + i * 16 + kblk * 4 + r;
      const float bv = biasS[c];
      float* oc = outn + (size_t)c * LLEN + l0;
#pragma unroll
      for (int j = 0; j < 4; ++j) {
        oc[j * 16 + lrow] = acc[i][j][r] - bv;
      }
    }
  }
}

extern "C" void kernel_launch(void* const* d_in, const int* in_sizes, int n_in,
                              void* d_out, int out_size, void* d_ws, size_t ws_size,
                              hipStream_t stream) {
  const float* X = (const float*)d_in[0];
  float* out = (float*)d_out;
  float* ws = (float*)d_ws;
  const size_t MSZ = (size_t)CCH * CCH;   // 65536 floats

  float* G    = ws;
  float* Y0   = ws + 1 * MSZ;
  float* Y1   = ws + 2 * MSZ;
  float* Z0   = ws + 3 * MSZ;
  float* Z1   = ws + 4 * MSZ;
  float* T    = ws + 5 * MSZ;
  ushort* WMh = (ushort*)(ws + 6 * MSZ);            // 65536 ushorts = MSZ/2 floats
  ushort* WMl = (ushort*)(ws + 6 * MSZ + MSZ / 2);
  float* msum = ws + 7 * MSZ;
  float* bias = msum + CCH;
  float* scal = bias + CCH;               // [0] = 1/sqrt(s)

  hipMemsetAsync(G, 0, MSZ * sizeof(float), stream);
  hipMemsetAsync(msum, 0, (2 * CCH + 2) * sizeof(float), stream);

  gram_kernel<<<dim3(GSPLIT, 3), 256, 0, stream>>>(X, G, msum);
  norm_kernel<<<256, 256, 0, stream>>>(G, msum, Y0, scal);

  // NS iter 0 (Z = I): T = 3I - Y0 elementwise, Z0 = 0.5*T, Y1 = 0.5*Y0*T
  ns0_kernel<<<256, 256, 0, stream>>>(Y0, T, Z0);
  nsY_kernel<<<10, 256, 0, stream>>>(Y0, T, Y1);

  float* Yc = Y1; float* Zc = Z0; float* Yn = Y0; float* Zn = Z1;
  for (int it = 1; it < NS_ITERS; ++it) {
    nsT_kernel<<<10, 256, 0, stream>>>(Zc, Yc, T);
    nsYZ_kernel<<<20, 256, 0, stream>>>(Yc, Zc, T, Yn, Zn);
    float* tmp;
    tmp = Yc; Yc = Yn; Yn = tmp;
    tmp = Zc; Zc = Zn; Zn = tmp;
  }

  wmsplit_kernel<<<256, 256, 0, stream>>>(Zc, scal, WMh, WMl);
  bias_kernel<<<1, CCH, 0, stream>>>(Zc, msum, scal, bias);
  whiten_kernel<<<dim3(LLEN / 64, NBATCH), 256, 0, stream>>>(X, WMh, WMl, bias, out);
}